// Round 3
// baseline (8275.163 us; speedup 1.0000x reference)
//
#include <hip/hip_runtime.h>
#include <stdint.h>

typedef unsigned short u16;
typedef short short8 __attribute__((ext_vector_type(8)));
typedef float f32x4 __attribute__((ext_vector_type(4)));
typedef unsigned int u32x4 __attribute__((ext_vector_type(4)));

#define NS 256
#define CIN 2304
#define CH 512
#define HW 49
#define MTOT (NS*HW)   // 12544

__device__ __forceinline__ float b2f(u16 u){
    union { unsigned int v; float f; } x; x.v = ((unsigned int)u) << 16; return x.f;
}
__device__ __forceinline__ u16 f2b(float f){
    unsigned int u = __builtin_bit_cast(unsigned int, f);
    u += 0x7FFFu + ((u >> 16) & 1u);
    return (u16)(u >> 16);
}
__device__ __forceinline__ u16 load_as_bf16(const void* p, size_t i, int isf32){
    return isf32 ? f2b(((const float*)p)[i]) : ((const u16*)p)[i];
}

#if defined(__has_builtin)
#if __has_builtin(__builtin_amdgcn_global_load_lds)
#define HAS_GLL 1
#endif
#endif

__device__ __forceinline__ void gll16(const u16* g, u16* l){
#ifdef HAS_GLL
    __builtin_amdgcn_global_load_lds(
        (const __attribute__((address_space(1))) unsigned int*)g,
        (__attribute__((address_space(3))) unsigned int*)l, 16, 0, 0);
#endif
}

// ---------------- dtype detector ---------------------------------------------
__global__ void k_detect(const u16* __restrict__ src, int* __restrict__ flag){
    int cnt = 0;
    for (int i = threadIdx.x; i < 8192; i += 256){
        int e = (src[i] >> 7) & 0xFF;
        cnt += (e >= 0x90);
    }
    for (int off = 32; off; off >>= 1) cnt += __shfl_down(cnt, off, 64);
    __shared__ int sh[4];
    int wave = threadIdx.x >> 6, lane = threadIdx.x & 63;
    if (lane == 0) sh[wave] = cnt;
    __syncthreads();
    if (threadIdx.x == 0)
        flag[0] = (sh[0] + sh[1] + sh[2] + sh[3] > 200) ? 1 : 0;
}

// ---------------- small converter --------------------------------------------
__global__ void k_convert_small(const void* __restrict__ src, u16* __restrict__ dst,
                                int n, const int* __restrict__ flag){
    const int isf32 = flag[0];
    for (int i = blockIdx.x*256 + threadIdx.x; i < n; i += gridDim.x*256)
        dst[i] = load_as_bf16(src, i, isf32);
}

// ---------------- zero helpers (ws is poisoned 0xAA each launch) -------------
__global__ void k_zero_f32(float* __restrict__ p, int n){
    for (int i = blockIdx.x*256 + threadIdx.x; i < n; i += gridDim.x*256)
        p[i] = 0.f;
}
__global__ void k_zero_u16(u16* __restrict__ p, int n){
    for (int i = threadIdx.x; i < n; i += 256) p[i] = 0;
}

// ---------------- transpose bbox_feat [n][2304][49] -> in_t [n][49][2304] ----
__global__ void k_transpose_in(const void* __restrict__ src, u16* __restrict__ dst,
                               const int* __restrict__ flag){
    const int isf32 = flag[0];
    __shared__ u16 tile[64*50];
    const int n = blockIdx.x;
    const int c0 = blockIdx.y * 64;
    const size_t sbase = ((size_t)n*CIN + c0)*HW;
    for (int idx = threadIdx.x; idx < 64*49; idx += 256){
        int cc = idx / 49, hw = idx - cc*49;
        tile[cc*50 + hw] = load_as_bf16(src, sbase + cc*HW + hw, isf32);
    }
    __syncthreads();
    u16* d = dst + (size_t)n*HW*CIN + c0;
    for (int idx = threadIdx.x; idx < 49*64; idx += 256){
        int hw = idx >> 6, cc = idx & 63;
        d[(size_t)hw*CIN + cc] = tile[cc*50 + hw];
    }
}

// ---------------- weight transpose [512][Cin][9] -> [512][9][Cin] ------------
__global__ void k_transpose_w(const void* __restrict__ w, u16* __restrict__ wt,
                              int Cin, const int* __restrict__ flag){
    const int isf32 = flag[0];
    size_t total = (size_t)CH * Cin * 9;
    for (size_t d = (size_t)blockIdx.x*blockDim.x + threadIdx.x; d < total;
         d += (size_t)gridDim.x*blockDim.x){
        int c  = (int)(d % Cin);
        size_t t = d / Cin;
        int kk = (int)(t % 9);
        int co = (int)(t / 9);
        wt[d] = load_as_bf16(w, ((size_t)co*Cin + c)*9 + kk, isf32);
    }
}

// ---------------- unified 3x3 conv, implicit GEMM, global_load_lds staging ---
// tile 128x128, BK=32, 4 waves (2x2 of 64x64), 16x16x32 bf16 MFMA.
// mode 0: split-K partial (kk in [3z,3z+3)) -> atomicAdd fp32 part[m][co]
// mode 1: z selects (w0->out0 | w1->out1), full kk, bf16 channel-last out
// mode 2: z selects (inA,w0 | inB,w1); out NCHW d_out[branch=z] = acc+resid
__global__ __launch_bounds__(256) void k_conv(
        const u16* __restrict__ inA, const u16* __restrict__ inB,
        const u16* __restrict__ zp,
        const u16* __restrict__ w0, const u16* __restrict__ w1, int Cin,
        float* __restrict__ part,
        u16* __restrict__ out0, u16* __restrict__ out1,
        const u16* __restrict__ resid, void* __restrict__ out_nchw,
        const int* __restrict__ dtf, int mode)
{
    __shared__ __align__(16) u16 As[128*32];
    __shared__ __align__(16) u16 Bs[128*32];
    const int tid  = threadIdx.x;
    const int wave = tid >> 6, lane = tid & 63;
    const int z    = blockIdx.z;
    const int m0   = blockIdx.x * 128;
    const int co0  = blockIdx.y * 128;

    const u16* in = (mode == 2 && z) ? inB : inA;
    const u16* wt = (mode != 0 && z) ? w1 : w0;
    const int kk0 = (mode == 0) ? 3*z     : 0;
    const int kk1 = (mode == 0) ? 3*z + 3 : 9;

    // staging slots: wave handles A rows [wave*32, wave*32+32) and same B rows,
    // as 2 chunks of 16 rows; lane L covers row chunk+(L>>2), bytes (L&3)*16.
    int srow[2], sm[2], sy[2], sx[2], sco[2];
    for (int s = 0; s < 2; ++s){
        srow[s] = wave*32 + s*16 + (lane >> 2);
        sm[s] = m0 + srow[s];
        int n = sm[s] / 49, hw = sm[s] - n*49;
        sy[s] = hw / 7; sx[s] = hw - sy[s]*7;
        sco[s] = co0 + srow[s];
    }
    const int lcol = (lane & 3) * 8;       // element offset within 32-el row
    u16* ldsA[2]; u16* ldsB[2];
    for (int s = 0; s < 2; ++s){
        ldsA[s] = &As[(wave*32 + s*16)*32];
        ldsB[s] = &Bs[(wave*32 + s*16)*32];
    }

    f32x4 acc[4][4];
    for (int i = 0; i < 4; ++i)
        for (int j = 0; j < 4; ++j)
            acc[i][j] = (f32x4){0.f, 0.f, 0.f, 0.f};

    const int wm = (wave & 1) * 64, wn = (wave >> 1) * 64;
    int aoff[4], boff[4];
    for (int i = 0; i < 4; ++i){
        aoff[i] = (wm + i*16 + (lane & 15))*32 + (lane >> 4)*8;
        boff[i] = (wn + i*16 + (lane & 15))*32 + (lane >> 4)*8;
    }

    for (int kk = kk0; kk < kk1; ++kk){
        const int dy = kk/3 - 1, dx = kk - (kk/3)*3 - 1;
        const u16* aptr[2]; const u16* bptr[2];
        for (int s = 0; s < 2; ++s){
            int yy = sy[s] + dy, xx = sx[s] + dx;
            bool valid = ((unsigned)yy < 7u) & ((unsigned)xx < 7u);
            const u16* base = valid ? in + (size_t)(sm[s] + dy*7 + dx)*Cin : zp;
            aptr[s] = base + lcol;
            bptr[s] = wt + ((size_t)sco[s]*9 + kk)*Cin + lcol;
        }
        for (int c0 = 0; c0 < Cin; c0 += 32){
            __syncthreads();          // frag reads of previous step complete
#ifdef HAS_GLL
            gll16(aptr[0], ldsA[0]);
            gll16(aptr[1], ldsA[1]);
            gll16(bptr[0], ldsB[0]);
            gll16(bptr[1], ldsB[1]);
            __builtin_amdgcn_s_waitcnt(0x0f70);   // vmcnt(0)
#else
            {
                u32x4 va0 = *(const u32x4*)aptr[0];
                u32x4 va1 = *(const u32x4*)aptr[1];
                u32x4 vb0 = *(const u32x4*)bptr[0];
                u32x4 vb1 = *(const u32x4*)bptr[1];
                *(u32x4*)(ldsA[0] + lane*8) = va0;
                *(u32x4*)(ldsA[1] + lane*8) = va1;
                *(u32x4*)(ldsB[0] + lane*8) = vb0;
                *(u32x4*)(ldsB[1] + lane*8) = vb1;
            }
#endif
            __syncthreads();
            short8 af[4], bfr[4];
            for (int i = 0; i < 4; ++i) af[i]  = *(const short8*)(&As[aoff[i]]);
            for (int j = 0; j < 4; ++j) bfr[j] = *(const short8*)(&Bs[boff[j]]);
            for (int i = 0; i < 4; ++i)
                for (int j = 0; j < 4; ++j)
                    acc[i][j] = __builtin_amdgcn_mfma_f32_16x16x32_bf16(
                                    af[i], bfr[j], acc[i][j], 0, 0, 0);
            for (int s = 0; s < 2; ++s){ aptr[s] += 32; bptr[s] += 32; }
        }
    }

    // epilogue: D row=(lane>>4)*4+r, col=lane&15
    u16* ocl = (mode == 1) ? (z ? out1 : out0) : nullptr;
    const int isf32 = (mode == 2) ? dtf[0] : 0;
    for (int i = 0; i < 4; ++i){
        int mbase = m0 + wm + i*16 + (lane >> 4)*4;
        for (int j = 0; j < 4; ++j){
            int co = co0 + wn + j*16 + (lane & 15);
            for (int r = 0; r < 4; ++r){
                int m = mbase + r;
                float v = acc[i][j][r];
                if (mode == 0){
                    atomicAdd(&part[(size_t)m*CH + co], v);
                } else if (mode == 1){
                    ocl[(size_t)m*CH + co] = f2b(v);
                } else {
                    float res = b2f(resid[(size_t)m*CH + co]);
                    int n = m / 49, hw = m - (m/49)*49;
                    size_t off = (size_t)z*MTOT*CH + ((size_t)n*CH + co)*HW + hw;
                    float o = v + res;
                    if (isf32) ((float*)out_nchw)[off] = o;
                    else       ((u16*)out_nchw)[off]   = f2b(o);
                }
            }
        }
    }
}

// ---------------- finalize feat: fp32 partials -> bf16 channel-last ----------
__global__ void k_finalize(const float* __restrict__ part, u16* __restrict__ feat){
    int i = blockIdx.x*256 + threadIdx.x;
    int n = MTOT*CH;
    for (; i < n; i += gridDim.x*256) feat[i] = f2b(part[i]);
}

// ---------------- q conv: spatially-constant 5-ch input ----------------------
__global__ void k_qconv(const u16* __restrict__ status, const u16* __restrict__ rois,
                        const u16* __restrict__ wq, u16* __restrict__ q_t, int branch){
    const int n = blockIdx.x, hw = blockIdx.y;
    const int co = threadIdx.x;          // 512 threads
    const int y = hw / 7, x = hw - (hw/7)*7;
    float sval[5];
    sval[0] = b2f(status[n*2 + branch]);
    for (int c = 1; c < 5; ++c) sval[c] = b2f(rois[n*5 + c]);
    float acc = 0.f;
    for (int c = 0; c < 5; ++c){
        float wsum = 0.f;
        for (int ky = 0; ky < 3; ++ky){
            int yy = y + ky - 1; if (yy < 0 || yy >= 7) continue;
            for (int kx = 0; kx < 3; ++kx){
                int xx = x + kx - 1; if (xx < 0 || xx >= 7) continue;
                wsum += b2f(wq[(co*5 + c)*9 + ky*3 + kx]);
            }
        }
        acc += sval[c] * wsum;
    }
    q_t[((size_t)n*HW + hw)*CH + co] = f2b(acc);
}

// ---------------- attention per (g, hw) --------------------------------------
__global__ void k_att(const u16* __restrict__ q_t, const u16* __restrict__ k_t,
                      const u16* __restrict__ v_t, u16* __restrict__ virt_t){
    __shared__ u16 qs[16*520], ks[16*520], vs[16*520];
    __shared__ float ls[256], ps[256];
    const int hw = blockIdx.x, g = blockIdx.y;
    const int tid = threadIdx.x;
    for (int idx = tid; idx < 16*512; idx += 256){
        int i = idx >> 9, c = idx & 511;
        size_t m = (size_t)(g*16 + i)*HW + hw;
        qs[i*520 + c] = q_t[m*CH + c];
        ks[i*520 + c] = k_t[m*CH + c];
        vs[i*520 + c] = v_t[m*CH + c];
    }
    __syncthreads();
    const int i = tid >> 4, j = tid & 15;
    float dot = 0.f;
    for (int c = 0; c < 512; ++c) dot += b2f(qs[i*520 + c]) * b2f(ks[j*520 + c]);
    ls[tid] = dot * 0.04419417382415922f;   // 1/sqrt(512)
    __syncthreads();
    float mx = -1e30f;
    for (int jj = 0; jj < 16; ++jj) mx = fmaxf(mx, ls[i*16 + jj]);
    float ssum = 0.f;
    for (int jj = 0; jj < 16; ++jj) ssum += __expf(ls[i*16 + jj] - mx);
    ps[tid] = __expf(ls[tid] - mx) / ssum;
    __syncthreads();
    const int c0 = tid & 15, ii = tid >> 4;
    for (int c = c0; c < 512; c += 16){
        float a = 0.f;
        for (int jj = 0; jj < 16; ++jj) a += ps[ii*16 + jj] * b2f(vs[jj*520 + c]);
        virt_t[((size_t)(g*16 + ii)*HW + hw)*CH + c] = f2b(a);
    }
}

// ---------------- per-sample mean/rstd over 512*49 ---------------------------
__global__ void k_stats(const u16* __restrict__ virt_t, float* __restrict__ stats){
    const int n = blockIdx.x;
    const u16* p = virt_t + (size_t)n * (CH*HW);
    float s = 0.f, s2 = 0.f;
    for (int idx = threadIdx.x; idx < CH*HW; idx += 256){
        float v = b2f(p[idx]); s += v; s2 += v*v;
    }
    for (int off = 32; off; off >>= 1){
        s  += __shfl_down(s,  off, 64);
        s2 += __shfl_down(s2, off, 64);
    }
    __shared__ float bs[4], bs2[4];
    int wave = threadIdx.x >> 6, lane = threadIdx.x & 63;
    if (lane == 0){ bs[wave] = s; bs2[wave] = s2; }
    __syncthreads();
    if (threadIdx.x == 0){
        float t = 0.f, t2 = 0.f;
        for (int w = 0; w < 4; ++w){ t += bs[w]; t2 += bs2[w]; }
        float mean = t / (float)(CH*HW);
        float var  = t2 / (float)(CH*HW) - mean*mean;
        stats[n*2]   = mean;
        stats[n*2+1] = rsqrtf(var + 1e-5f);
    }
}

// ---------------- normalize + relu ------------------------------------------
__global__ void k_norm(const u16* __restrict__ virt_t, const float* __restrict__ stats,
                       const u16* __restrict__ gamma, const u16* __restrict__ beta,
                       u16* __restrict__ h_t){
    size_t idx = (size_t)blockIdx.x*256 + threadIdx.x;
    if (idx >= (size_t)NS*HW*CH) return;
    int c = (int)(idx & 511);
    int m = (int)(idx >> 9);
    int n = m / 49;
    float v = b2f(virt_t[idx]);
    float h = (v - stats[n*2]) * stats[n*2+1] * b2f(gamma[c]) + b2f(beta[c]);
    h_t[idx] = f2b(fmaxf(h, 0.f));
}

extern "C" void kernel_launch(void* const* d_in, const int* in_sizes, int n_in,
                              void* d_out, int out_size, void* d_ws, size_t ws_size,
                              hipStream_t stream) {
    const void* status   = d_in[0];
    const void* rois     = d_in[1];
    const void* bbox     = d_in[2];
    const void* w_reduce = d_in[3];
    const void* w_q1     = d_in[4];
    const void* w_q2     = d_in[5];
    const void* w_k1     = d_in[6];
    const void* w_v1     = d_in[7];
    const void* w_k2     = d_in[8];
    const void* w_v2     = d_in[9];
    const void* w_c1     = d_in[10];
    const void* w_c2     = d_in[11];
    const void* gamma    = d_in[12];
    const void* beta     = d_in[13];

    // ---- region map (bytes), peak ~118 MB; round-2's 120.4 MB was safe ----
    char* p = (char*)d_ws;
    const size_t SZ_INT = (size_t)MTOT*CIN*2;   // 57,802,752  R_in
    const size_t SZ_WRT = (size_t)CH*9*CIN*2;   // 21,233,664  R_wr
    const size_t SZ_F32 = (size_t)MTOT*CH*4;    // 25,690,112  R_f32
    const size_t SZ_T   = (size_t)MTOT*CH*2;    // 12,845,056
    const size_t SZ_WT  = (size_t)CH*9*CH*2;    //  4,718,592

    char* R_in  = p;                    // phase1: in_t | phase2: wt6,q,virt
    char* R_wr  = p + SZ_INT;           // phase1: w_r_t | phase2: h0
    char* R_f32 = R_wr + SZ_WRT;        // phase1: featf32 | phase2: k,v / h1
    u16*  feat  = (u16*)(R_f32 + SZ_F32);               // live all phase2
    char* SM    = (char*)feat + SZ_T;                   // smalls

    u16*   in_t    = (u16*)R_in;
    u16*   w_r_t   = (u16*)R_wr;
    float* featf32 = (float*)R_f32;
    u16*   wt[6];
    for (int i = 0; i < 6; ++i) wt[i] = (u16*)(R_in + i*SZ_WT);   // 28.3MB
    u16*   q_t  = (u16*)(R_in + 6*SZ_WT);                          // +12.85
    u16*   virt = (u16*)(R_in + 6*SZ_WT + SZ_T);                   // +12.85 = 54MB
    u16*   h0   = (u16*)R_wr;
    u16*   k_t  = (u16*)R_f32;
    u16*   v_t  = (u16*)(R_f32 + SZ_T);
    u16*   h1   = (u16*)R_f32;          // overwrites k_t after att of branch 1

    float* stats    = (float*)SM;
    int*   flag     = (int*)(SM + 4096);
    u16*   status_c = (u16*)(SM + 8192);
    u16*   rois_c   = status_c + 1024;
    u16*   gamma_c  = rois_c + 2048;
    u16*   beta_c   = gamma_c + 512;
    u16*   wq_c0    = beta_c + 512;
    u16*   wq_c1    = wq_c0 + CH*5*9;
    u16*   zp       = wq_c1 + CH*5*9;   // zero page, CIN elements

    k_detect<<<1, 256, 0, stream>>>((const u16*)bbox, flag);
    k_transpose_in<<<dim3(NS, CIN/64), 256, 0, stream>>>(bbox, in_t, flag);
    k_transpose_w<<<1024, 256, 0, stream>>>(w_reduce, w_r_t, CIN, flag);
    k_convert_small<<<2, 256, 0, stream>>>(status, status_c, NS*2, flag);
    k_convert_small<<<5, 256, 0, stream>>>(rois, rois_c, NS*5, flag);
    k_convert_small<<<2, 256, 0, stream>>>(gamma, gamma_c, CH, flag);
    k_convert_small<<<2, 256, 0, stream>>>(beta, beta_c, CH, flag);
    k_convert_small<<<90, 256, 0, stream>>>(w_q1, wq_c0, CH*5*9, flag);
    k_convert_small<<<90, 256, 0, stream>>>(w_q2, wq_c1, CH*5*9, flag);
    k_zero_f32<<<2048, 256, 0, stream>>>(featf32, MTOT*CH);
    k_zero_u16<<<1, 256, 0, stream>>>(zp, CIN);

    // reduce conv: split-K over kk triplets, fp32 atomic partials
    k_conv<<<dim3(MTOT/128, CH/128, 3), 256, 0, stream>>>(
        in_t, nullptr, zp, w_r_t, nullptr, CIN,
        featf32, nullptr, nullptr, nullptr, nullptr, flag, 0);
    k_finalize<<<2048, 256, 0, stream>>>(featf32, feat);

    // weight transposes for the 6 CH convs (into R_in, now dead)
    const void* wsrc[6] = {w_k1, w_v1, w_k2, w_v2, w_c1, w_c2};
    for (int i = 0; i < 6; ++i)
        k_transpose_w<<<512, 256, 0, stream>>>(wsrc[i], wt[i], CH, flag);

    for (int br = 0; br < 2; ++br){
        k_qconv<<<dim3(NS, HW), 512, 0, stream>>>(status_c, rois_c,
                                                  br ? wq_c1 : wq_c0, q_t, br);
        // fused k+v conv (z=0 -> k_t, z=1 -> v_t)
        k_conv<<<dim3(MTOT/128, CH/128, 2), 256, 0, stream>>>(
            feat, nullptr, zp, wt[br*2 + 0], wt[br*2 + 1], CH,
            nullptr, k_t, v_t, nullptr, nullptr, flag, 1);
        k_att<<<dim3(HW, 16), 256, 0, stream>>>(q_t, k_t, v_t, virt);
        k_stats<<<NS, 256, 0, stream>>>(virt, stats);
        k_norm<<<(NS*HW*CH)/256, 256, 0, stream>>>(virt, stats, gamma_c, beta_c,
                                                   br ? h1 : h0);
    }
    // fused final convs for both branches (z = branch)
    k_conv<<<dim3(MTOT/128, CH/128, 2), 256, 0, stream>>>(
        h0, h1, zp, wt[4], wt[5], CH,
        nullptr, nullptr, nullptr, feat, d_out, flag, 2);
}